// Round 1
// baseline (62.178 us; speedup 1.0000x reference)
//
#include <hip/hip_runtime.h>
#include <math.h>

namespace {
constexpr int kB  = 2048;
constexpr int kSW = 2048;     // short width
constexpr int kLW = 8192;     // long width
constexpr int kLP = kLW / 2;  // pooled length = 4096
constexpr int kSROWS = 4;     // batch rows per block (short)
constexpr int kLROWS = 2;     // batch rows per block (long)
}

// ---------------- short branch: conv(k=3,p=1) -> relu -> dot with 2 weight rows ----------------
__global__ __launch_bounds__(256) void short_branch_kernel(
    const float* __restrict__ xs, const float* __restrict__ cw,
    const float* __restrict__ cb, const float* __restrict__ lw,
    const float* __restrict__ lb, float* __restrict__ f) {
  __shared__ float red[kSROWS][2][4];
  const int tid = threadIdx.x;
  const int b0 = blockIdx.x * kSROWS;

  float w0[8], w1[8], w2[8], bias[8];
#pragma unroll
  for (int c = 0; c < 8; ++c) {
    w0[c] = cw[c * 3 + 0];
    w1[c] = cw[c * 3 + 1];
    w2[c] = cw[c * 3 + 2];
    bias[c] = cb[c];
  }

  float acc[kSROWS][2];
#pragma unroll
  for (int r = 0; r < kSROWS; ++r) { acc[r][0] = 0.f; acc[r][1] = 0.f; }

  for (int it = 0; it < kSW / 256; ++it) {
    const int p = tid + it * 256;
    float xm[kSROWS], x0[kSROWS], xp[kSROWS];
#pragma unroll
    for (int r = 0; r < kSROWS; ++r) {
      const float* x = xs + (size_t)(b0 + r) * kSW;
      xm[r] = (p > 0)       ? x[p - 1] : 0.f;
      x0[r] = x[p];
      xp[r] = (p < kSW - 1) ? x[p + 1] : 0.f;
    }
#pragma unroll
    for (int c = 0; c < 8; ++c) {
      const float lwa = lw[c * kSW + p];
      const float lwb = lw[8 * kSW + c * kSW + p];
#pragma unroll
      for (int r = 0; r < kSROWS; ++r) {
        float v = fmaf(w0[c], xm[r], fmaf(w1[c], x0[r], fmaf(w2[c], xp[r], bias[c])));
        v = fmaxf(v, 0.f);
        acc[r][0] = fmaf(v, lwa, acc[r][0]);
        acc[r][1] = fmaf(v, lwb, acc[r][1]);
      }
    }
  }

#pragma unroll
  for (int r = 0; r < kSROWS; ++r)
#pragma unroll
    for (int o = 0; o < 2; ++o) {
      float a = acc[r][o];
#pragma unroll
      for (int off = 32; off > 0; off >>= 1) a += __shfl_down(a, off);
      if ((tid & 63) == 0) red[r][o][tid >> 6] = a;
    }
  __syncthreads();
  if (tid < kSROWS * 2) {
    const int r = tid >> 1, o = tid & 1;
    f[(size_t)(b0 + r) * 4 + o] =
        red[r][o][0] + red[r][o][1] + red[r][o][2] + red[r][o][3] + lb[o];
  }
}

// ------------- long branch: conv(k=5,p=2) -> relu -> maxpool(2) -> dot with 2 weight rows -------------
__global__ __launch_bounds__(256) void long_branch_kernel(
    const float* __restrict__ xl, const float* __restrict__ cw,
    const float* __restrict__ cb, const float* __restrict__ lw,
    const float* __restrict__ lb, float* __restrict__ f) {
  __shared__ float red[kLROWS][2][4];
  const int tid = threadIdx.x;
  const int b0 = blockIdx.x * kLROWS;

  float w[8][5], bias[8];
#pragma unroll
  for (int c = 0; c < 8; ++c) {
#pragma unroll
    for (int k = 0; k < 5; ++k) w[c][k] = cw[c * 5 + k];
    bias[c] = cb[c];
  }

  float acc[kLROWS][2];
#pragma unroll
  for (int r = 0; r < kLROWS; ++r) { acc[r][0] = 0.f; acc[r][1] = 0.f; }

  for (int it = 0; it < kLP / 256; ++it) {
    const int q = tid + it * 256;  // pooled position, conv positions 2q and 2q+1
    float xv[kLROWS][6];           // x[2q-2 .. 2q+3]
#pragma unroll
    for (int r = 0; r < kLROWS; ++r) {
      const float2* x2 = reinterpret_cast<const float2*>(xl + (size_t)(b0 + r) * kLW);
      float2 m2 = (q > 0)       ? x2[q - 1] : make_float2(0.f, 0.f);
      float2 c2 = x2[q];
      float2 p2 = (q < kLP - 1) ? x2[q + 1] : make_float2(0.f, 0.f);
      xv[r][0] = m2.x; xv[r][1] = m2.y;
      xv[r][2] = c2.x; xv[r][3] = c2.y;
      xv[r][4] = p2.x; xv[r][5] = p2.y;
    }
#pragma unroll
    for (int c = 0; c < 8; ++c) {
      const float lwa = lw[c * kLP + q];
      const float lwb = lw[8 * kLP + c * kLP + q];
#pragma unroll
      for (int r = 0; r < kLROWS; ++r) {
        float v0 = fmaf(w[c][0], xv[r][0],
                   fmaf(w[c][1], xv[r][1],
                   fmaf(w[c][2], xv[r][2],
                   fmaf(w[c][3], xv[r][3],
                   fmaf(w[c][4], xv[r][4], bias[c])))));
        float v1 = fmaf(w[c][0], xv[r][1],
                   fmaf(w[c][1], xv[r][2],
                   fmaf(w[c][2], xv[r][3],
                   fmaf(w[c][3], xv[r][4],
                   fmaf(w[c][4], xv[r][5], bias[c])))));
        float m = fmaxf(fmaxf(v0, v1), 0.f);
        acc[r][0] = fmaf(m, lwa, acc[r][0]);
        acc[r][1] = fmaf(m, lwb, acc[r][1]);
      }
    }
  }

#pragma unroll
  for (int r = 0; r < kLROWS; ++r)
#pragma unroll
    for (int o = 0; o < 2; ++o) {
      float a = acc[r][o];
#pragma unroll
      for (int off = 32; off > 0; off >>= 1) a += __shfl_down(a, off);
      if ((tid & 63) == 0) red[r][o][tid >> 6] = a;
    }
  __syncthreads();
  if (tid < kLROWS * 2) {
    const int r = tid >> 1, o = tid & 1;
    f[(size_t)(b0 + r) * 4 + 2 + o] =
        red[r][o][0] + red[r][o][1] + red[r][o][2] + red[r][o][3] + lb[o];
  }
}

// ---------------- 4-qubit statevector circuit + final linear ----------------
// Wire w <-> bit (3-w) of the flat 16-amplitude index (any consistent bijection is valid).
template <int MASK>
__device__ __forceinline__ void apply_1q(float (&ar)[16], float (&ai)[16],
                                         float u00r, float u00i, float u01r, float u01i,
                                         float u10r, float u10i, float u11r, float u11i) {
#pragma unroll
  for (int i = 0; i < 16; ++i) {
    if (!(i & MASK)) {
      const int j = i | MASK;
      const float a0r = ar[i], a0i = ai[i];
      const float a1r = ar[j], a1i = ai[j];
      ar[i] = u00r * a0r - u00i * a0i + u01r * a1r - u01i * a1i;
      ai[i] = u00r * a0i + u00i * a0r + u01r * a1i + u01i * a1r;
      ar[j] = u10r * a0r - u10i * a0i + u11r * a1r - u11i * a1i;
      ai[j] = u10r * a0i + u10i * a0r + u11r * a1i + u11i * a1r;
    }
  }
}

template <int MASK>
__device__ __forceinline__ void apply_ry(float (&ar)[16], float (&ai)[16], float half_t) {
  float s, c;
  sincosf(half_t, &s, &c);
  apply_1q<MASK>(ar, ai, c, 0.f, -s, 0.f, s, 0.f, c, 0.f);
}

// Rot(phi, theta, omega) = RZ(omega) @ RY(theta) @ RZ(phi)
// U00 =  ct * e^{-i(phi+omega)/2}   U01 = -st * e^{+i(phi-omega)/2}
// U10 =  st * e^{-i(phi-omega)/2}   U11 =  ct * e^{+i(phi+omega)/2}
template <int MASK>
__device__ __forceinline__ void apply_rot(float (&ar)[16], float (&ai)[16],
                                          float phi, float theta, float omega) {
  float st, ct; sincosf(0.5f * theta, &st, &ct);
  float sa, ca; sincosf(0.5f * (phi + omega), &sa, &ca);
  float sm, cm; sincosf(0.5f * (phi - omega), &sm, &cm);
  apply_1q<MASK>(ar, ai,
                 ct * ca, -ct * sa,
                 -st * cm, -st * sm,
                 st * cm, -st * sm,
                 ct * ca, ct * sa);
}

template <int MC, int MT>
__device__ __forceinline__ void apply_cnot(float (&ar)[16], float (&ai)[16]) {
#pragma unroll
  for (int i = 0; i < 16; ++i) {
    if ((i & MC) && !(i & MT)) {
      const int j = i | MT;
      float t;
      t = ar[i]; ar[i] = ar[j]; ar[j] = t;
      t = ai[i]; ai[i] = ai[j]; ai[j] = t;
    }
  }
}

__global__ __launch_bounds__(256) void quantum_kernel(
    const float* __restrict__ f, const float* __restrict__ rw,
    const float* __restrict__ fcw, const float* __restrict__ fcb,
    float* __restrict__ out) {
  const int b = blockIdx.x * 256 + threadIdx.x;
  if (b >= kB) return;

  float ar[16], ai[16];
#pragma unroll
  for (int i = 0; i < 16; ++i) { ar[i] = 0.f; ai[i] = 0.f; }
  ar[0] = 1.f;

  const float kHalfPi = 1.57079632679489662f;
  apply_ry<8>(ar, ai, kHalfPi * f[b * 4 + 0]);
  apply_ry<4>(ar, ai, kHalfPi * f[b * 4 + 1]);
  apply_ry<2>(ar, ai, kHalfPi * f[b * 4 + 2]);
  apply_ry<1>(ar, ai, kHalfPi * f[b * 4 + 3]);

  // layer 0, r = 1: CNOT (0,1)(1,2)(2,3)(3,0)
  apply_rot<8>(ar, ai, rw[0], rw[1], rw[2]);
  apply_rot<4>(ar, ai, rw[3], rw[4], rw[5]);
  apply_rot<2>(ar, ai, rw[6], rw[7], rw[8]);
  apply_rot<1>(ar, ai, rw[9], rw[10], rw[11]);
  apply_cnot<8, 4>(ar, ai);
  apply_cnot<4, 2>(ar, ai);
  apply_cnot<2, 1>(ar, ai);
  apply_cnot<1, 8>(ar, ai);

  // layer 1, r = 2: CNOT (0,2)(1,3)(2,0)(3,1)
  apply_rot<8>(ar, ai, rw[12], rw[13], rw[14]);
  apply_rot<4>(ar, ai, rw[15], rw[16], rw[17]);
  apply_rot<2>(ar, ai, rw[18], rw[19], rw[20]);
  apply_rot<1>(ar, ai, rw[21], rw[22], rw[23]);
  apply_cnot<8, 2>(ar, ai);
  apply_cnot<4, 1>(ar, ai);
  apply_cnot<2, 8>(ar, ai);
  apply_cnot<1, 4>(ar, ai);

  // layer 2, r = 3: CNOT (0,3)(1,0)(2,1)(3,2)
  apply_rot<8>(ar, ai, rw[24], rw[25], rw[26]);
  apply_rot<4>(ar, ai, rw[27], rw[28], rw[29]);
  apply_rot<2>(ar, ai, rw[30], rw[31], rw[32]);
  apply_rot<1>(ar, ai, rw[33], rw[34], rw[35]);
  apply_cnot<8, 1>(ar, ai);
  apply_cnot<4, 8>(ar, ai);
  apply_cnot<2, 4>(ar, ai);
  apply_cnot<1, 2>(ar, ai);

  float z0 = 0.f, z1 = 0.f, z2 = 0.f, z3 = 0.f;
#pragma unroll
  for (int i = 0; i < 16; ++i) {
    const float p = ar[i] * ar[i] + ai[i] * ai[i];
    z0 += (i & 8) ? -p : p;
    z1 += (i & 4) ? -p : p;
    z2 += (i & 2) ? -p : p;
    z3 += (i & 1) ? -p : p;
  }
  out[b] = fcb[0] + z0 * fcw[0] + z1 * fcw[1] + z2 * fcw[2] + z3 * fcw[3];
}

extern "C" void kernel_launch(void* const* d_in, const int* in_sizes, int n_in,
                              void* d_out, int out_size, void* d_ws, size_t ws_size,
                              hipStream_t stream) {
  const float* xs     = (const float*)d_in[0];
  const float* xl     = (const float*)d_in[1];
  const float* cs_cw  = (const float*)d_in[2];
  const float* cs_cb  = (const float*)d_in[3];
  const float* cs_lw  = (const float*)d_in[4];
  const float* cs_lb  = (const float*)d_in[5];
  const float* cl_cw  = (const float*)d_in[6];
  const float* cl_cb  = (const float*)d_in[7];
  const float* cl_lw  = (const float*)d_in[8];
  const float* cl_lb  = (const float*)d_in[9];
  const float* rw     = (const float*)d_in[10];
  const float* fcw    = (const float*)d_in[11];
  const float* fcb    = (const float*)d_in[12];
  float* out = (float*)d_out;
  float* f   = (float*)d_ws;  // [kB, 4] features

  hipLaunchKernelGGL(short_branch_kernel, dim3(kB / kSROWS), dim3(256), 0, stream,
                     xs, cs_cw, cs_cb, cs_lw, cs_lb, f);
  hipLaunchKernelGGL(long_branch_kernel, dim3(kB / kLROWS), dim3(256), 0, stream,
                     xl, cl_cw, cl_cb, cl_lw, cl_lb, f);
  hipLaunchKernelGGL(quantum_kernel, dim3(kB / 256), dim3(256), 0, stream,
                     f, rw, fcw, fcb, out);
}

// Round 2
// 49.442 us; speedup vs baseline: 1.2576x; 1.2576x over previous
//
#include <hip/hip_runtime.h>
#include <math.h>

namespace {
constexpr int kB  = 2048;
constexpr int kSW = 2048;     // short width
constexpr int kLW = 8192;     // long width
constexpr int kLP = kLW / 2;  // pooled length = 4096
constexpr int kROWS = 4;      // batch rows per block (both branches)
constexpr int kLBLKS = kB / kROWS;  // 512 long-branch blocks
constexpr int kSBLKS = kB / kROWS;  // 512 short-branch blocks
}

// ------------- long branch: conv(k=5,p=2) -> relu -> maxpool(2) -> dot(2 rows) -------------
// 4 batch rows / block, 4 consecutive pooled positions / thread / chunk.
__device__ __forceinline__ void long_branch(
    int blk, const float* __restrict__ xl, const float* __restrict__ cw,
    const float* __restrict__ cb, const float* __restrict__ lw,
    const float* __restrict__ lb, float* __restrict__ f) {
  __shared__ float red[kROWS][2][4];
  const int tid = threadIdx.x;
  const int b0 = blk * kROWS;

  float wgt[8][5], bias[8];
#pragma unroll
  for (int c = 0; c < 8; ++c) {
#pragma unroll
    for (int k = 0; k < 5; ++k) wgt[c][k] = cw[c * 5 + k];
    bias[c] = cb[c];
  }

  float acc[kROWS][2];
#pragma unroll
  for (int r = 0; r < kROWS; ++r) { acc[r][0] = 0.f; acc[r][1] = 0.f; }

  for (int ch = 0; ch < kLP / 1024; ++ch) {   // 4 chunks
    const int p0 = ch * 1024 + tid * 4;       // pooled base (mult of 4)
    const int s  = 2 * p0;                    // conv-input base (mult of 8)

    // window w[r][0..11] = x[s-2 .. s+9] (zero-padded at edges)
    float w[kROWS][12];
#pragma unroll
    for (int r = 0; r < kROWS; ++r) {
      const float* x = xl + (size_t)(b0 + r) * kLW;
      float2 hm = (p0 > 0) ? *reinterpret_cast<const float2*>(x + s - 2)
                           : make_float2(0.f, 0.f);
      float4 f0 = *reinterpret_cast<const float4*>(x + s);
      float4 f1 = *reinterpret_cast<const float4*>(x + s + 4);
      float2 f2 = (s + 8 < kLW) ? *reinterpret_cast<const float2*>(x + s + 8)
                                : make_float2(0.f, 0.f);
      w[r][0] = hm.x; w[r][1] = hm.y;
      w[r][2] = f0.x; w[r][3] = f0.y; w[r][4] = f0.z; w[r][5] = f0.w;
      w[r][6] = f1.x; w[r][7] = f1.y; w[r][8] = f1.z; w[r][9] = f1.w;
      w[r][10] = f2.x; w[r][11] = f2.y;
    }

#pragma unroll
    for (int c = 0; c < 8; ++c) {
      float4 la4 = *reinterpret_cast<const float4*>(lw + (size_t)c * kLP + p0);
      float4 lb4 = *reinterpret_cast<const float4*>(lw + (size_t)(8 + c) * kLP + p0);
      const float la[4] = {la4.x, la4.y, la4.z, la4.w};
      const float lbv[4] = {lb4.x, lb4.y, lb4.z, lb4.w};
#pragma unroll
      for (int r = 0; r < kROWS; ++r) {
#pragma unroll
        for (int u = 0; u < 4; ++u) {
          float v0 = fmaf(wgt[c][0], w[r][2 * u + 0],
                     fmaf(wgt[c][1], w[r][2 * u + 1],
                     fmaf(wgt[c][2], w[r][2 * u + 2],
                     fmaf(wgt[c][3], w[r][2 * u + 3],
                     fmaf(wgt[c][4], w[r][2 * u + 4], bias[c])))));
          float v1 = fmaf(wgt[c][0], w[r][2 * u + 1],
                     fmaf(wgt[c][1], w[r][2 * u + 2],
                     fmaf(wgt[c][2], w[r][2 * u + 3],
                     fmaf(wgt[c][3], w[r][2 * u + 4],
                     fmaf(wgt[c][4], w[r][2 * u + 5], bias[c])))));
          const float m = fmaxf(fmaxf(v0, v1), 0.f);
          acc[r][0] = fmaf(m, la[u], acc[r][0]);
          acc[r][1] = fmaf(m, lbv[u], acc[r][1]);
        }
      }
    }
  }

#pragma unroll
  for (int r = 0; r < kROWS; ++r)
#pragma unroll
    for (int o = 0; o < 2; ++o) {
      float a = acc[r][o];
#pragma unroll
      for (int off = 32; off > 0; off >>= 1) a += __shfl_down(a, off);
      if ((tid & 63) == 0) red[r][o][tid >> 6] = a;
    }
  __syncthreads();
  if (tid < kROWS * 2) {
    const int r = tid >> 1, o = tid & 1;
    f[(size_t)(b0 + r) * 4 + 2 + o] =
        red[r][o][0] + red[r][o][1] + red[r][o][2] + red[r][o][3] + lb[o];
  }
}

// ------------- short branch: conv(k=3,p=1) -> relu -> dot(2 rows) -------------
__device__ __forceinline__ void short_branch(
    int blk, const float* __restrict__ xs, const float* __restrict__ cw,
    const float* __restrict__ cb, const float* __restrict__ lw,
    const float* __restrict__ lb, float* __restrict__ f) {
  __shared__ float red[kROWS][2][4];
  const int tid = threadIdx.x;
  const int b0 = blk * kROWS;

  float wgt[8][3], bias[8];
#pragma unroll
  for (int c = 0; c < 8; ++c) {
#pragma unroll
    for (int k = 0; k < 3; ++k) wgt[c][k] = cw[c * 3 + k];
    bias[c] = cb[c];
  }

  float acc[kROWS][2];
#pragma unroll
  for (int r = 0; r < kROWS; ++r) { acc[r][0] = 0.f; acc[r][1] = 0.f; }

  for (int ch = 0; ch < kSW / 1024; ++ch) {   // 2 chunks
    const int p0 = ch * 1024 + tid * 4;       // position base (mult of 4)

    // window w[r][0..5] = x[p0-1 .. p0+4]
    float w[kROWS][6];
#pragma unroll
    for (int r = 0; r < kROWS; ++r) {
      const float* x = xs + (size_t)(b0 + r) * kSW;
      float xm = (p0 > 0) ? x[p0 - 1] : 0.f;
      float4 f0 = *reinterpret_cast<const float4*>(x + p0);
      float xp = (p0 + 4 < kSW) ? x[p0 + 4] : 0.f;
      w[r][0] = xm;
      w[r][1] = f0.x; w[r][2] = f0.y; w[r][3] = f0.z; w[r][4] = f0.w;
      w[r][5] = xp;
    }

#pragma unroll
    for (int c = 0; c < 8; ++c) {
      float4 la4 = *reinterpret_cast<const float4*>(lw + (size_t)c * kSW + p0);
      float4 lb4 = *reinterpret_cast<const float4*>(lw + (size_t)(8 + c) * kSW + p0);
      const float la[4] = {la4.x, la4.y, la4.z, la4.w};
      const float lbv[4] = {lb4.x, lb4.y, lb4.z, lb4.w};
#pragma unroll
      for (int r = 0; r < kROWS; ++r) {
#pragma unroll
        for (int u = 0; u < 4; ++u) {
          float v = fmaf(wgt[c][0], w[r][u],
                    fmaf(wgt[c][1], w[r][u + 1],
                    fmaf(wgt[c][2], w[r][u + 2], bias[c])));
          const float m = fmaxf(v, 0.f);
          acc[r][0] = fmaf(m, la[u], acc[r][0]);
          acc[r][1] = fmaf(m, lbv[u], acc[r][1]);
        }
      }
    }
  }

#pragma unroll
  for (int r = 0; r < kROWS; ++r)
#pragma unroll
    for (int o = 0; o < 2; ++o) {
      float a = acc[r][o];
#pragma unroll
      for (int off = 32; off > 0; off >>= 1) a += __shfl_down(a, off);
      if ((tid & 63) == 0) red[r][o][tid >> 6] = a;
    }
  __syncthreads();
  if (tid < kROWS * 2) {
    const int r = tid >> 1, o = tid & 1;
    f[(size_t)(b0 + r) * 4 + o] =
        red[r][o][0] + red[r][o][1] + red[r][o][2] + red[r][o][3] + lb[o];
  }
}

// ------------- fused feature kernel: long blocks first, short blocks after -------------
__global__ __launch_bounds__(256) void features_kernel(
    const float* __restrict__ xs, const float* __restrict__ cs_cw,
    const float* __restrict__ cs_cb, const float* __restrict__ cs_lw,
    const float* __restrict__ cs_lb,
    const float* __restrict__ xl, const float* __restrict__ cl_cw,
    const float* __restrict__ cl_cb, const float* __restrict__ cl_lw,
    const float* __restrict__ cl_lb, float* __restrict__ f) {
  const int bid = blockIdx.x;
  if (bid < kLBLKS)
    long_branch(bid, xl, cl_cw, cl_cb, cl_lw, cl_lb, f);
  else
    short_branch(bid - kLBLKS, xs, cs_cw, cs_cb, cs_lw, cs_lb, f);
}

// ---------------- 4-qubit statevector circuit + final linear ----------------
template <int MASK>
__device__ __forceinline__ void apply_1q(float (&ar)[16], float (&ai)[16],
                                         float u00r, float u00i, float u01r, float u01i,
                                         float u10r, float u10i, float u11r, float u11i) {
#pragma unroll
  for (int i = 0; i < 16; ++i) {
    if (!(i & MASK)) {
      const int j = i | MASK;
      const float a0r = ar[i], a0i = ai[i];
      const float a1r = ar[j], a1i = ai[j];
      ar[i] = u00r * a0r - u00i * a0i + u01r * a1r - u01i * a1i;
      ai[i] = u00r * a0i + u00i * a0r + u01r * a1i + u01i * a1r;
      ar[j] = u10r * a0r - u10i * a0i + u11r * a1r - u11i * a1i;
      ai[j] = u10r * a0i + u10i * a0r + u11r * a1i + u11i * a1r;
    }
  }
}

template <int MASK>
__device__ __forceinline__ void apply_ry(float (&ar)[16], float (&ai)[16], float half_t) {
  float s, c;
  sincosf(half_t, &s, &c);
  apply_1q<MASK>(ar, ai, c, 0.f, -s, 0.f, s, 0.f, c, 0.f);
}

// Rot(phi, theta, omega) = RZ(omega) @ RY(theta) @ RZ(phi)
template <int MASK>
__device__ __forceinline__ void apply_rot(float (&ar)[16], float (&ai)[16],
                                          float phi, float theta, float omega) {
  float st, ct; sincosf(0.5f * theta, &st, &ct);
  float sa, ca; sincosf(0.5f * (phi + omega), &sa, &ca);
  float sm, cm; sincosf(0.5f * (phi - omega), &sm, &cm);
  apply_1q<MASK>(ar, ai,
                 ct * ca, -ct * sa,
                 -st * cm, -st * sm,
                 st * cm, -st * sm,
                 ct * ca, ct * sa);
}

template <int MC, int MT>
__device__ __forceinline__ void apply_cnot(float (&ar)[16], float (&ai)[16]) {
#pragma unroll
  for (int i = 0; i < 16; ++i) {
    if ((i & MC) && !(i & MT)) {
      const int j = i | MT;
      float t;
      t = ar[i]; ar[i] = ar[j]; ar[j] = t;
      t = ai[i]; ai[i] = ai[j]; ai[j] = t;
    }
  }
}

__global__ __launch_bounds__(256) void quantum_kernel(
    const float* __restrict__ f, const float* __restrict__ rw,
    const float* __restrict__ fcw, const float* __restrict__ fcb,
    float* __restrict__ out) {
  const int b = blockIdx.x * 256 + threadIdx.x;
  if (b >= kB) return;

  float ar[16], ai[16];
#pragma unroll
  for (int i = 0; i < 16; ++i) { ar[i] = 0.f; ai[i] = 0.f; }
  ar[0] = 1.f;

  const float kHalfPi = 1.57079632679489662f;
  apply_ry<8>(ar, ai, kHalfPi * f[b * 4 + 0]);
  apply_ry<4>(ar, ai, kHalfPi * f[b * 4 + 1]);
  apply_ry<2>(ar, ai, kHalfPi * f[b * 4 + 2]);
  apply_ry<1>(ar, ai, kHalfPi * f[b * 4 + 3]);

  // layer 0, r = 1
  apply_rot<8>(ar, ai, rw[0], rw[1], rw[2]);
  apply_rot<4>(ar, ai, rw[3], rw[4], rw[5]);
  apply_rot<2>(ar, ai, rw[6], rw[7], rw[8]);
  apply_rot<1>(ar, ai, rw[9], rw[10], rw[11]);
  apply_cnot<8, 4>(ar, ai);
  apply_cnot<4, 2>(ar, ai);
  apply_cnot<2, 1>(ar, ai);
  apply_cnot<1, 8>(ar, ai);

  // layer 1, r = 2
  apply_rot<8>(ar, ai, rw[12], rw[13], rw[14]);
  apply_rot<4>(ar, ai, rw[15], rw[16], rw[17]);
  apply_rot<2>(ar, ai, rw[18], rw[19], rw[20]);
  apply_rot<1>(ar, ai, rw[21], rw[22], rw[23]);
  apply_cnot<8, 2>(ar, ai);
  apply_cnot<4, 1>(ar, ai);
  apply_cnot<2, 8>(ar, ai);
  apply_cnot<1, 4>(ar, ai);

  // layer 2, r = 3
  apply_rot<8>(ar, ai, rw[24], rw[25], rw[26]);
  apply_rot<4>(ar, ai, rw[27], rw[28], rw[29]);
  apply_rot<2>(ar, ai, rw[30], rw[31], rw[32]);
  apply_rot<1>(ar, ai, rw[33], rw[34], rw[35]);
  apply_cnot<8, 1>(ar, ai);
  apply_cnot<4, 8>(ar, ai);
  apply_cnot<2, 4>(ar, ai);
  apply_cnot<1, 2>(ar, ai);

  float z0 = 0.f, z1 = 0.f, z2 = 0.f, z3 = 0.f;
#pragma unroll
  for (int i = 0; i < 16; ++i) {
    const float p = ar[i] * ar[i] + ai[i] * ai[i];
    z0 += (i & 8) ? -p : p;
    z1 += (i & 4) ? -p : p;
    z2 += (i & 2) ? -p : p;
    z3 += (i & 1) ? -p : p;
  }
  out[b] = fcb[0] + z0 * fcw[0] + z1 * fcw[1] + z2 * fcw[2] + z3 * fcw[3];
}

extern "C" void kernel_launch(void* const* d_in, const int* in_sizes, int n_in,
                              void* d_out, int out_size, void* d_ws, size_t ws_size,
                              hipStream_t stream) {
  const float* xs     = (const float*)d_in[0];
  const float* xl     = (const float*)d_in[1];
  const float* cs_cw  = (const float*)d_in[2];
  const float* cs_cb  = (const float*)d_in[3];
  const float* cs_lw  = (const float*)d_in[4];
  const float* cs_lb  = (const float*)d_in[5];
  const float* cl_cw  = (const float*)d_in[6];
  const float* cl_cb  = (const float*)d_in[7];
  const float* cl_lw  = (const float*)d_in[8];
  const float* cl_lb  = (const float*)d_in[9];
  const float* rw     = (const float*)d_in[10];
  const float* fcw    = (const float*)d_in[11];
  const float* fcb    = (const float*)d_in[12];
  float* out = (float*)d_out;
  float* f   = (float*)d_ws;  // [kB, 4] features

  hipLaunchKernelGGL(features_kernel, dim3(kLBLKS + kSBLKS), dim3(256), 0, stream,
                     xs, cs_cw, cs_cb, cs_lw, cs_lb,
                     xl, cl_cw, cl_cb, cl_lw, cl_lb, f);
  hipLaunchKernelGGL(quantum_kernel, dim3(kB / 256), dim3(256), 0, stream,
                     f, rw, fcw, fcb, out);
}

// Round 3
// 46.086 us; speedup vs baseline: 1.3492x; 1.0728x over previous
//
#include <hip/hip_runtime.h>
#include <math.h>

namespace {
constexpr int kB  = 2048;
constexpr int kSW = 2048;     // short width
constexpr int kLW = 8192;     // long width
constexpr int kLP = kLW / 2;  // pooled length = 4096
constexpr int kROWS = 4;      // batch rows per block
constexpr int kLBLKS = (kB / kROWS) * 2;  // 1024: long, split into 2 position-halves
constexpr int kSBLKS = (kB / kROWS) * 2;  // 1024: short, split into 2 position-halves
}

// ------------- long branch half: conv(k=5,p=2) -> relu -> maxpool(2) -> partial dot -------------
// 4 batch rows / block, half the pooled positions (2048), 4 positions / thread / chunk.
__device__ __forceinline__ void long_half(
    int blk, int h, const float* __restrict__ xl, const float* __restrict__ cw,
    const float* __restrict__ cb, const float* __restrict__ lw,
    float* __restrict__ part) {
  __shared__ float red[kROWS][2][4];
  const int tid = threadIdx.x;
  const int b0 = blk * kROWS;

  float wgt[8][5], bias[8];
#pragma unroll
  for (int c = 0; c < 8; ++c) {
#pragma unroll
    for (int k = 0; k < 5; ++k) wgt[c][k] = cw[c * 5 + k];
    bias[c] = cb[c];
  }

  float acc[kROWS][2];
#pragma unroll
  for (int r = 0; r < kROWS; ++r) { acc[r][0] = 0.f; acc[r][1] = 0.f; }

  for (int ch = 0; ch < 2; ++ch) {
    const int p0 = h * 2048 + ch * 1024 + tid * 4;  // pooled base (mult of 4)
    const int s  = 2 * p0;                          // conv-input base (mult of 8)

    // window w[r][0..11] = x[s-2 .. s+9] (zero-padded at edges)
    float w[kROWS][12];
#pragma unroll
    for (int r = 0; r < kROWS; ++r) {
      const float* x = xl + (size_t)(b0 + r) * kLW;
      float2 hm = (p0 > 0) ? *reinterpret_cast<const float2*>(x + s - 2)
                           : make_float2(0.f, 0.f);
      float4 f0 = *reinterpret_cast<const float4*>(x + s);
      float4 f1 = *reinterpret_cast<const float4*>(x + s + 4);
      float2 f2 = (s + 8 < kLW) ? *reinterpret_cast<const float2*>(x + s + 8)
                                : make_float2(0.f, 0.f);
      w[r][0] = hm.x; w[r][1] = hm.y;
      w[r][2] = f0.x; w[r][3] = f0.y; w[r][4] = f0.z; w[r][5] = f0.w;
      w[r][6] = f1.x; w[r][7] = f1.y; w[r][8] = f1.z; w[r][9] = f1.w;
      w[r][10] = f2.x; w[r][11] = f2.y;
    }

#pragma unroll
    for (int c = 0; c < 8; ++c) {
      float4 la4 = *reinterpret_cast<const float4*>(lw + (size_t)c * kLP + p0);
      float4 lb4 = *reinterpret_cast<const float4*>(lw + (size_t)(8 + c) * kLP + p0);
      const float la[4] = {la4.x, la4.y, la4.z, la4.w};
      const float lbv[4] = {lb4.x, lb4.y, lb4.z, lb4.w};
#pragma unroll
      for (int r = 0; r < kROWS; ++r) {
#pragma unroll
        for (int u = 0; u < 4; ++u) {
          float v0 = fmaf(wgt[c][0], w[r][2 * u + 0],
                     fmaf(wgt[c][1], w[r][2 * u + 1],
                     fmaf(wgt[c][2], w[r][2 * u + 2],
                     fmaf(wgt[c][3], w[r][2 * u + 3],
                     fmaf(wgt[c][4], w[r][2 * u + 4], bias[c])))));
          float v1 = fmaf(wgt[c][0], w[r][2 * u + 1],
                     fmaf(wgt[c][1], w[r][2 * u + 2],
                     fmaf(wgt[c][2], w[r][2 * u + 3],
                     fmaf(wgt[c][3], w[r][2 * u + 4],
                     fmaf(wgt[c][4], w[r][2 * u + 5], bias[c])))));
          const float m = fmaxf(fmaxf(v0, v1), 0.f);
          acc[r][0] = fmaf(m, la[u], acc[r][0]);
          acc[r][1] = fmaf(m, lbv[u], acc[r][1]);
        }
      }
    }
  }

#pragma unroll
  for (int r = 0; r < kROWS; ++r)
#pragma unroll
    for (int o = 0; o < 2; ++o) {
      float a = acc[r][o];
#pragma unroll
      for (int off = 32; off > 0; off >>= 1) a += __shfl_down(a, off);
      if ((tid & 63) == 0) red[r][o][tid >> 6] = a;
    }
  __syncthreads();
  if (tid < kROWS * 2) {
    const int r = tid >> 1, o = tid & 1;
    part[(size_t)h * kB * 4 + (size_t)(b0 + r) * 4 + 2 + o] =
        red[r][o][0] + red[r][o][1] + red[r][o][2] + red[r][o][3];
  }
}

// ------------- short branch half: conv(k=3,p=1) -> relu -> partial dot -------------
__device__ __forceinline__ void short_half(
    int blk, int h, const float* __restrict__ xs, const float* __restrict__ cw,
    const float* __restrict__ cb, const float* __restrict__ lw,
    float* __restrict__ part) {
  __shared__ float red[kROWS][2][4];
  const int tid = threadIdx.x;
  const int b0 = blk * kROWS;

  float wgt[8][3], bias[8];
#pragma unroll
  for (int c = 0; c < 8; ++c) {
#pragma unroll
    for (int k = 0; k < 3; ++k) wgt[c][k] = cw[c * 3 + k];
    bias[c] = cb[c];
  }

  float acc[kROWS][2];
#pragma unroll
  for (int r = 0; r < kROWS; ++r) { acc[r][0] = 0.f; acc[r][1] = 0.f; }

  {
    const int p0 = h * 1024 + tid * 4;  // position base (mult of 4)

    // window w[r][0..5] = x[p0-1 .. p0+4]
    float w[kROWS][6];
#pragma unroll
    for (int r = 0; r < kROWS; ++r) {
      const float* x = xs + (size_t)(b0 + r) * kSW;
      float xm = (p0 > 0) ? x[p0 - 1] : 0.f;
      float4 f0 = *reinterpret_cast<const float4*>(x + p0);
      float xp = (p0 + 4 < kSW) ? x[p0 + 4] : 0.f;
      w[r][0] = xm;
      w[r][1] = f0.x; w[r][2] = f0.y; w[r][3] = f0.z; w[r][4] = f0.w;
      w[r][5] = xp;
    }

#pragma unroll
    for (int c = 0; c < 8; ++c) {
      float4 la4 = *reinterpret_cast<const float4*>(lw + (size_t)c * kSW + p0);
      float4 lb4 = *reinterpret_cast<const float4*>(lw + (size_t)(8 + c) * kSW + p0);
      const float la[4] = {la4.x, la4.y, la4.z, la4.w};
      const float lbv[4] = {lb4.x, lb4.y, lb4.z, lb4.w};
#pragma unroll
      for (int r = 0; r < kROWS; ++r) {
#pragma unroll
        for (int u = 0; u < 4; ++u) {
          float v = fmaf(wgt[c][0], w[r][u],
                    fmaf(wgt[c][1], w[r][u + 1],
                    fmaf(wgt[c][2], w[r][u + 2], bias[c])));
          const float m = fmaxf(v, 0.f);
          acc[r][0] = fmaf(m, la[u], acc[r][0]);
          acc[r][1] = fmaf(m, lbv[u], acc[r][1]);
        }
      }
    }
  }

#pragma unroll
  for (int r = 0; r < kROWS; ++r)
#pragma unroll
    for (int o = 0; o < 2; ++o) {
      float a = acc[r][o];
#pragma unroll
      for (int off = 32; off > 0; off >>= 1) a += __shfl_down(a, off);
      if ((tid & 63) == 0) red[r][o][tid >> 6] = a;
    }
  __syncthreads();
  if (tid < kROWS * 2) {
    const int r = tid >> 1, o = tid & 1;
    part[(size_t)h * kB * 4 + (size_t)(b0 + r) * 4 + o] =
        red[r][o][0] + red[r][o][1] + red[r][o][2] + red[r][o][3];
  }
}

// ------------- fused feature kernel -------------
__global__ __launch_bounds__(256) void features_kernel(
    const float* __restrict__ xs, const float* __restrict__ cs_cw,
    const float* __restrict__ cs_cb, const float* __restrict__ cs_lw,
    const float* __restrict__ xl, const float* __restrict__ cl_cw,
    const float* __restrict__ cl_cb, const float* __restrict__ cl_lw,
    float* __restrict__ part) {
  const int bid = blockIdx.x;
  if (bid < kLBLKS)
    long_half(bid >> 1, bid & 1, xl, cl_cw, cl_cb, cl_lw, part);
  else {
    const int s = bid - kLBLKS;
    short_half(s >> 1, s & 1, xs, cs_cw, cs_cb, cs_lw, part);
  }
}

// ---------------- 4-qubit statevector circuit + final linear ----------------
template <int MASK>
__device__ __forceinline__ void apply_1q(float (&ar)[16], float (&ai)[16],
                                         float u00r, float u00i, float u01r, float u01i,
                                         float u10r, float u10i, float u11r, float u11i) {
#pragma unroll
  for (int i = 0; i < 16; ++i) {
    if (!(i & MASK)) {
      const int j = i | MASK;
      const float a0r = ar[i], a0i = ai[i];
      const float a1r = ar[j], a1i = ai[j];
      ar[i] = u00r * a0r - u00i * a0i + u01r * a1r - u01i * a1i;
      ai[i] = u00r * a0i + u00i * a0r + u01r * a1i + u01i * a1r;
      ar[j] = u10r * a0r - u10i * a0i + u11r * a1r - u11i * a1i;
      ai[j] = u10r * a0i + u10i * a0r + u11r * a1i + u11i * a1r;
    }
  }
}

template <int MASK>
__device__ __forceinline__ void apply_ry(float (&ar)[16], float (&ai)[16], float half_t) {
  float s, c;
  sincosf(half_t, &s, &c);
  apply_1q<MASK>(ar, ai, c, 0.f, -s, 0.f, s, 0.f, c, 0.f);
}

// Rot(phi, theta, omega) = RZ(omega) @ RY(theta) @ RZ(phi)
template <int MASK>
__device__ __forceinline__ void apply_rot(float (&ar)[16], float (&ai)[16],
                                          float phi, float theta, float omega) {
  float st, ct; sincosf(0.5f * theta, &st, &ct);
  float sa, ca; sincosf(0.5f * (phi + omega), &sa, &ca);
  float sm, cm; sincosf(0.5f * (phi - omega), &sm, &cm);
  apply_1q<MASK>(ar, ai,
                 ct * ca, -ct * sa,
                 -st * cm, -st * sm,
                 st * cm, -st * sm,
                 ct * ca, ct * sa);
}

template <int MC, int MT>
__device__ __forceinline__ void apply_cnot(float (&ar)[16], float (&ai)[16]) {
#pragma unroll
  for (int i = 0; i < 16; ++i) {
    if ((i & MC) && !(i & MT)) {
      const int j = i | MT;
      float t;
      t = ar[i]; ar[i] = ar[j]; ar[j] = t;
      t = ai[i]; ai[i] = ai[j]; ai[j] = t;
    }
  }
}

__global__ __launch_bounds__(64) void quantum_kernel(
    const float* __restrict__ part, const float* __restrict__ cs_lb,
    const float* __restrict__ cl_lb, const float* __restrict__ rw,
    const float* __restrict__ fcw, const float* __restrict__ fcb,
    float* __restrict__ out) {
  const int b = blockIdx.x * 64 + threadIdx.x;
  if (b >= kB) return;

  const float f0 = part[(size_t)b * 4 + 0] + part[(size_t)kB * 4 + b * 4 + 0] + cs_lb[0];
  const float f1 = part[(size_t)b * 4 + 1] + part[(size_t)kB * 4 + b * 4 + 1] + cs_lb[1];
  const float f2 = part[(size_t)b * 4 + 2] + part[(size_t)kB * 4 + b * 4 + 2] + cl_lb[0];
  const float f3 = part[(size_t)b * 4 + 3] + part[(size_t)kB * 4 + b * 4 + 3] + cl_lb[1];

  float ar[16], ai[16];
#pragma unroll
  for (int i = 0; i < 16; ++i) { ar[i] = 0.f; ai[i] = 0.f; }
  ar[0] = 1.f;

  const float kHalfPi = 1.57079632679489662f;
  apply_ry<8>(ar, ai, kHalfPi * f0);
  apply_ry<4>(ar, ai, kHalfPi * f1);
  apply_ry<2>(ar, ai, kHalfPi * f2);
  apply_ry<1>(ar, ai, kHalfPi * f3);

  // layer 0, r = 1
  apply_rot<8>(ar, ai, rw[0], rw[1], rw[2]);
  apply_rot<4>(ar, ai, rw[3], rw[4], rw[5]);
  apply_rot<2>(ar, ai, rw[6], rw[7], rw[8]);
  apply_rot<1>(ar, ai, rw[9], rw[10], rw[11]);
  apply_cnot<8, 4>(ar, ai);
  apply_cnot<4, 2>(ar, ai);
  apply_cnot<2, 1>(ar, ai);
  apply_cnot<1, 8>(ar, ai);

  // layer 1, r = 2
  apply_rot<8>(ar, ai, rw[12], rw[13], rw[14]);
  apply_rot<4>(ar, ai, rw[15], rw[16], rw[17]);
  apply_rot<2>(ar, ai, rw[18], rw[19], rw[20]);
  apply_rot<1>(ar, ai, rw[21], rw[22], rw[23]);
  apply_cnot<8, 2>(ar, ai);
  apply_cnot<4, 1>(ar, ai);
  apply_cnot<2, 8>(ar, ai);
  apply_cnot<1, 4>(ar, ai);

  // layer 2, r = 3
  apply_rot<8>(ar, ai, rw[24], rw[25], rw[26]);
  apply_rot<4>(ar, ai, rw[27], rw[28], rw[29]);
  apply_rot<2>(ar, ai, rw[30], rw[31], rw[32]);
  apply_rot<1>(ar, ai, rw[33], rw[34], rw[35]);
  apply_cnot<8, 1>(ar, ai);
  apply_cnot<4, 8>(ar, ai);
  apply_cnot<2, 4>(ar, ai);
  apply_cnot<1, 2>(ar, ai);

  float z0 = 0.f, z1 = 0.f, z2 = 0.f, z3 = 0.f;
#pragma unroll
  for (int i = 0; i < 16; ++i) {
    const float p = ar[i] * ar[i] + ai[i] * ai[i];
    z0 += (i & 8) ? -p : p;
    z1 += (i & 4) ? -p : p;
    z2 += (i & 2) ? -p : p;
    z3 += (i & 1) ? -p : p;
  }
  out[b] = fcb[0] + z0 * fcw[0] + z1 * fcw[1] + z2 * fcw[2] + z3 * fcw[3];
}

extern "C" void kernel_launch(void* const* d_in, const int* in_sizes, int n_in,
                              void* d_out, int out_size, void* d_ws, size_t ws_size,
                              hipStream_t stream) {
  const float* xs     = (const float*)d_in[0];
  const float* xl     = (const float*)d_in[1];
  const float* cs_cw  = (const float*)d_in[2];
  const float* cs_cb  = (const float*)d_in[3];
  const float* cs_lw  = (const float*)d_in[4];
  const float* cs_lb  = (const float*)d_in[5];
  const float* cl_cw  = (const float*)d_in[6];
  const float* cl_cb  = (const float*)d_in[7];
  const float* cl_lw  = (const float*)d_in[8];
  const float* cl_lb  = (const float*)d_in[9];
  const float* rw     = (const float*)d_in[10];
  const float* fcw    = (const float*)d_in[11];
  const float* fcb    = (const float*)d_in[12];
  float* out  = (float*)d_out;
  float* part = (float*)d_ws;  // [2][kB][4] partial features

  hipLaunchKernelGGL(features_kernel, dim3(kLBLKS + kSBLKS), dim3(256), 0, stream,
                     xs, cs_cw, cs_cb, cs_lw,
                     xl, cl_cw, cl_cb, cl_lw, part);
  hipLaunchKernelGGL(quantum_kernel, dim3(kB / 64), dim3(64), 0, stream,
                     part, cs_lb, cl_lb, rw, fcw, fcb, out);
}